// Round 3
// baseline (455.503 us; speedup 1.0000x reference)
//
#include <hip/hip_runtime.h>

#define NPG 116          // nodes per graph
#define DEGC 32          // edges per node
#define EPG (NPG * DEGC) // 3712 edges per graph
#define HID 32
#define HID2 64
#define EPS 1e-5f

#define APAD 120         // A row stride (floats), 16B-aligned rows
#define AROWS 58         // conv2 builds A in two 58-row halves
#define NJC 29           // 116 floats = 29 float4

#define FMA4(acc, a, b)                                                        \
  acc.x += (a).x * (b).x; acc.y += (a).y * (b).y;                              \
  acc.z += (a).z * (b).z; acc.w += (a).w * (b).w;

#define HSUM4(v) (((v).x + (v).y) + ((v).z + (v).w))

// ---------------------------------------------------------------------------
// ws layout (floats):
//   [0,256)    stats: s1[32] q1[32] s2[64] q2[64]   (memset to 0 each launch)
//   [256,512)  coefs: a1[32] c1[32] a2[64] c2[64]
//   [512, +32N)   h1  (conv1 output)
//   [..,  +64N)   h2  (conv2 output)
//   [..,  +32G)   z   (FC1 pre-BN)
// ---------------------------------------------------------------------------

// Fused: stage x tile -> lin1 = x@W1 -> build normalized A -> h1 = A@lin1
// -> h1 + BN1 stat partials.  One block per graph.  LDS ~71 KB -> 2 blocks/CU.
__global__ __launch_bounds__(256) void k_conv1(const float* __restrict__ x,
                                               const int* __restrict__ ei,
                                               const float* __restrict__ ew,
                                               const float* __restrict__ W1,
                                               float* __restrict__ h1,
                                               float* __restrict__ stats,
                                               int N, int E) {
  __shared__ __align__(16) float A[NPG * APAD];   // first used as x tile
  __shared__ float l1[NPG * HID];
  __shared__ float degs[NPG];
  __shared__ float ss[HID], qs[HID];
  int g = blockIdx.x, tid = threadIdx.x;
  int nb = g * NPG, e0 = g * EPG;
  const int* rowp = ei;
  const int* colp = ei + E;

  for (int i = tid; i < NPG; i += 256) degs[i] = 1.0f;  // self-loop weight
  if (tid < HID) { ss[tid] = 0.0f; qs[tid] = 0.0f; }
  __syncthreads();

  // phase 1: stage x tile (float4), deg atomics, W1 column -> regs
  {
    const float4* xg = (const float4*)(x + (size_t)nb * 116);
    float4* xs4 = (float4*)A;
    for (int i = tid; i < 116 * NJC; i += 256) {
      int r = i / NJC, jc = i - r * NJC;
      xs4[r * 30 + jc] = xg[i];
    }
    for (int e = tid; e < EPG; e += 256) {
      int d = colp[e0 + e] - nb;
      atomicAdd(&degs[d], ew[e0 + e]);
    }
  }
  int c = tid & 31, rgrp = tid >> 5;  // 8 row groups x 15 rows
  float4 col[NJC];
#pragma unroll
  for (int kc = 0; kc < NJC; ++kc) {
    col[kc].x = W1[(4 * kc + 0) * 32 + c];
    col[kc].y = W1[(4 * kc + 1) * 32 + c];
    col[kc].z = W1[(4 * kc + 2) * 32 + c];
    col[kc].w = W1[(4 * kc + 3) * 32 + c];
  }
  __syncthreads();  // x tile staged, deg atomics done

  for (int i = tid; i < NPG; i += 256) degs[i] = rsqrtf(degs[i]);  // deg>=1

  // gemm1: l1[r][c] = sum_k x[r][k] * W1[k][c]  (2-row pairs for ILP)
  const float4* A4 = (const float4*)A;
  int rbase = rgrp * 15;
  for (int m = 0; m < 15; m += 2) {
    int ra = rbase + m, rb = ra + 1;
    if (ra >= NPG) break;
    bool hb = (m + 1 < 15) && (rb < NPG);
    const float4* pa = A4 + ra * 30;
    const float4* pb = A4 + rb * 30;
    float4 a0 = {0.f, 0.f, 0.f, 0.f}, a1v = {0.f, 0.f, 0.f, 0.f};
    if (hb) {
#pragma unroll
      for (int jc = 0; jc < NJC; ++jc) {
        FMA4(a0, pa[jc], col[jc]);
        FMA4(a1v, pb[jc], col[jc]);
      }
    } else {
#pragma unroll
      for (int jc = 0; jc < NJC; ++jc) { FMA4(a0, pa[jc], col[jc]); }
    }
    l1[ra * 32 + c] = HSUM4(a0);
    if (hb) l1[rb * 32 + c] = HSUM4(a1v);
  }
  __syncthreads();  // all x-tile reads done -> reuse A

  {
    float4 z4 = {0.f, 0.f, 0.f, 0.f};
    float4* Az = (float4*)A;
    for (int i = tid; i < 116 * 30; i += 256) Az[i] = z4;
  }
  __syncthreads();

  // build A:  A[d][s] += dinv[s]*ew*dinv[d];  self loops A[i][i] += dinv[i]^2
  for (int e = tid; e < EPG; e += 256) {
    int eg = e0 + e;
    int s = rowp[eg] - nb, d = colp[eg] - nb;
    atomicAdd(&A[d * APAD + s], degs[s] * ew[eg] * degs[d]);
  }
  for (int i = tid; i < NPG; i += 256)
    atomicAdd(&A[i * APAD + i], degs[i] * degs[i]);
  // reload col regs with this lane's l1 column (l1 complete since last sync)
#pragma unroll
  for (int kc = 0; kc < NJC; ++kc) {
    col[kc].x = l1[(4 * kc + 0) * 32 + c];
    col[kc].y = l1[(4 * kc + 1) * 32 + c];
    col[kc].z = l1[(4 * kc + 2) * 32 + c];
    col[kc].w = l1[(4 * kc + 3) * 32 + c];
  }
  __syncthreads();  // A complete

  float s_ = 0.0f, q_ = 0.0f;
  for (int m = 0; m < 15; m += 2) {
    int ra = rbase + m, rb = ra + 1;
    if (ra >= NPG) break;
    bool hb = (m + 1 < 15) && (rb < NPG);
    const float4* pa = A4 + ra * 30;
    const float4* pb = A4 + rb * 30;
    float4 a0 = {0.f, 0.f, 0.f, 0.f}, a1v = {0.f, 0.f, 0.f, 0.f};
    if (hb) {
#pragma unroll
      for (int jc = 0; jc < NJC; ++jc) {
        FMA4(a0, pa[jc], col[jc]);
        FMA4(a1v, pb[jc], col[jc]);
      }
    } else {
#pragma unroll
      for (int jc = 0; jc < NJC; ++jc) { FMA4(a0, pa[jc], col[jc]); }
    }
    float v0 = HSUM4(a0);
    h1[(size_t)(nb + ra) * HID + c] = v0;
    s_ += v0; q_ += v0 * v0;
    if (hb) {
      float v1 = HSUM4(a1v);
      h1[(size_t)(nb + rb) * HID + c] = v1;
      s_ += v1; q_ += v1 * v1;
    }
  }
  atomicAdd(&ss[c], s_);
  atomicAdd(&qs[c], q_);
  __syncthreads();
  if (tid < HID) {
    atomicAdd(&stats[tid], ss[tid]);
    atomicAdd(&stats[32 + tid], qs[tid]);
  }
}

// BN coefficients: a = g*rsqrt(var+eps), c = beta - mean*a
__global__ void k_coef(const float* __restrict__ s, const float* __restrict__ q,
                       const float* __restrict__ gamma, const float* __restrict__ beta,
                       float* __restrict__ a, float* __restrict__ cc,
                       float invN, int C) {
  int c = threadIdx.x;
  if (c < C) {
    float m = s[c] * invN;
    float v = q[c] * invN - m * m;
    float aa = gamma[c] * rsqrtf(v + EPS);
    a[c] = aa;
    cc[c] = beta[c] - m * aa;
  }
}

// Fused: ys = relu(a1*h1+c1) -> lin2 = ys@W2 -> A (two row halves) ->
// h2 = A@lin2 + BN2 stat partials.  LDS ~75 KB -> 2 blocks/CU.
__global__ __launch_bounds__(256) void k_conv2(const float* __restrict__ h1,
                                               const int* __restrict__ ei,
                                               const float* __restrict__ ew,
                                               const float* __restrict__ W2,
                                               const float* __restrict__ coef,
                                               float* __restrict__ h2,
                                               float* __restrict__ stats2,
                                               int N, int E) {
  __shared__ float4 ysv[NPG * 9];                 // ys, stride 36 floats
  __shared__ float l2[NPG * HID2];
  __shared__ __align__(16) float Ah[AROWS * APAD];
  __shared__ float degs[NPG];
  __shared__ float ss[HID2], qs[HID2];
  int g = blockIdx.x, tid = threadIdx.x;
  int nb = g * NPG, e0 = g * EPG;
  const int* rowp = ei;
  const int* colp = ei + E;

  for (int i = tid; i < NPG; i += 256) degs[i] = 1.0f;
  if (tid < HID2) { ss[tid] = 0.0f; qs[tid] = 0.0f; }
  __syncthreads();

  // phase 1: stage ys = relu(a1*h1+c1), deg atomics, zero Ah
  {
    const float4* hg = (const float4*)(h1 + (size_t)nb * HID);
    const float4* a4p = (const float4*)coef;         // a1[32]
    const float4* c4p = (const float4*)(coef + 32);  // c1[32]
    for (int i = tid; i < 116 * 8; i += 256) {
      int r = i >> 3, kc = i & 7;
      float4 hv = hg[i];
      float4 av = a4p[kc], cv = c4p[kc];
      float4 y;
      y.x = fmaxf(0.f, av.x * hv.x + cv.x);
      y.y = fmaxf(0.f, av.y * hv.y + cv.y);
      y.z = fmaxf(0.f, av.z * hv.z + cv.z);
      y.w = fmaxf(0.f, av.w * hv.w + cv.w);
      ysv[r * 9 + kc] = y;
    }
    for (int e = tid; e < EPG; e += 256) {
      int d = colp[e0 + e] - nb;
      atomicAdd(&degs[d], ew[e0 + e]);
    }
    float4 z4 = {0.f, 0.f, 0.f, 0.f};
    float4* Az = (float4*)Ah;
    for (int i = tid; i < AROWS * 30; i += 256) Az[i] = z4;
  }
  int c = tid & 63, rgrp = tid >> 6;  // 4 row groups
  float4 w2c[8];
#pragma unroll
  for (int kc = 0; kc < 8; ++kc) {
    w2c[kc].x = W2[(4 * kc + 0) * 64 + c];
    w2c[kc].y = W2[(4 * kc + 1) * 64 + c];
    w2c[kc].z = W2[(4 * kc + 2) * 64 + c];
    w2c[kc].w = W2[(4 * kc + 3) * 64 + c];
  }
  __syncthreads();

  for (int i = tid; i < NPG; i += 256) degs[i] = rsqrtf(degs[i]);
  __syncthreads();  // dinv ready, Ah zeroed

  // A-build half 0 (d<58) issued first (atomics overlap gemm2 compute)
  for (int e = tid; e < EPG; e += 256) {
    int eg = e0 + e;
    int s = rowp[eg] - nb, d = colp[eg] - nb;
    if (d < AROWS) atomicAdd(&Ah[d * APAD + s], degs[s] * ew[eg] * degs[d]);
  }
  if (tid < AROWS) atomicAdd(&Ah[tid * APAD + tid], degs[tid] * degs[tid]);

  // gemm2: l2[r][c] = sum_k ys[r][k]*W2[k][c]  (2-row pairs)
  for (int m = 0; m < 29; m += 2) {
    int ra = rgrp * 29 + m, rb = ra + 1;
    bool hb = (m + 1 < 29);
    float4 a0 = {0.f, 0.f, 0.f, 0.f}, a1v = {0.f, 0.f, 0.f, 0.f};
    if (hb) {
#pragma unroll
      for (int kc = 0; kc < 8; ++kc) {
        FMA4(a0, ysv[ra * 9 + kc], w2c[kc]);
        FMA4(a1v, ysv[rb * 9 + kc], w2c[kc]);
      }
    } else {
#pragma unroll
      for (int kc = 0; kc < 8; ++kc) { FMA4(a0, ysv[ra * 9 + kc], w2c[kc]); }
    }
    l2[ra * 64 + c] = HSUM4(a0);
    if (hb) l2[rb * 64 + c] = HSUM4(a1v);
  }
  __syncthreads();  // Ah half0 + l2 complete

  float4 col[NJC];
#pragma unroll
  for (int kc = 0; kc < NJC; ++kc) {
    col[kc].x = l2[(4 * kc + 0) * 64 + c];
    col[kc].y = l2[(4 * kc + 1) * 64 + c];
    col[kc].z = l2[(4 * kc + 2) * 64 + c];
    col[kc].w = l2[(4 * kc + 3) * 64 + c];
  }
  const float4* A4 = (const float4*)Ah;
  float s_ = 0.0f, q_ = 0.0f;
  int rbase = rgrp * 15;  // 15,15,15,13 rows per group within each half

#define OUT_HALF(ROW_OFF)                                                      \
  for (int m = 0; m < 15; m += 2) {                                            \
    int ra = rbase + m, rb = ra + 1;                                           \
    if (ra >= AROWS) break;                                                    \
    bool hb = (m + 1 < 15) && (rb < AROWS);                                    \
    const float4* pa = A4 + ra * 30;                                           \
    const float4* pb = A4 + rb * 30;                                           \
    float4 a0 = {0.f, 0.f, 0.f, 0.f}, a1v = {0.f, 0.f, 0.f, 0.f};              \
    if (hb) {                                                                  \
      _Pragma("unroll")                                                        \
      for (int jc = 0; jc < NJC; ++jc) {                                       \
        FMA4(a0, pa[jc], col[jc]);                                             \
        FMA4(a1v, pb[jc], col[jc]);                                            \
      }                                                                        \
    } else {                                                                   \
      _Pragma("unroll")                                                        \
      for (int jc = 0; jc < NJC; ++jc) { FMA4(a0, pa[jc], col[jc]); }          \
    }                                                                          \
    float v0 = HSUM4(a0);                                                      \
    h2[(size_t)(nb + (ROW_OFF) + ra) * HID2 + c] = v0;                         \
    s_ += v0; q_ += v0 * v0;                                                   \
    if (hb) {                                                                  \
      float v1 = HSUM4(a1v);                                                   \
      h2[(size_t)(nb + (ROW_OFF) + rb) * HID2 + c] = v1;                       \
      s_ += v1; q_ += v1 * v1;                                                 \
    }                                                                          \
  }

  OUT_HALF(0)
  __syncthreads();  // half0 Ah reads done

  {
    float4 z4 = {0.f, 0.f, 0.f, 0.f};
    float4* Az = (float4*)Ah;
    for (int i = tid; i < AROWS * 30; i += 256) Az[i] = z4;
  }
  __syncthreads();
  for (int e = tid; e < EPG; e += 256) {
    int eg = e0 + e;
    int s = rowp[eg] - nb, d = colp[eg] - nb;
    if (d >= AROWS)
      atomicAdd(&Ah[(d - AROWS) * APAD + s], degs[s] * ew[eg] * degs[d]);
  }
  if (tid < AROWS) {
    int i = tid + AROWS;
    atomicAdd(&Ah[tid * APAD + i], degs[i] * degs[i]);
  }
  __syncthreads();  // Ah half1 built

  OUT_HALF(AROWS)
#undef OUT_HALF

  atomicAdd(&ss[c], s_);
  atomicAdd(&qs[c], q_);
  __syncthreads();
  if (tid < HID2) {
    atomicAdd(&stats2[tid], ss[tid]);
    atomicAdd(&stats2[64 + tid], qs[tid]);
  }
}

// per-graph BN2+relu, mean/max pool, FC1 (emb[128] @ Wf1[128x32]) -> z
__global__ __launch_bounds__(256) void k_pool(const float* __restrict__ h2,
                                              const float* __restrict__ coef,
                                              const float* __restrict__ Wf1,
                                              float* __restrict__ z, int N) {
  __shared__ float4 psum4[256], pmax4[256];
  __shared__ __align__(16) float emb[128];
  int g = blockIdx.x, tid = threadIdx.x;
  int c4 = tid & 15, rg = tid >> 4;
  const float4* a4 = (const float4*)(coef + 64);
  const float4* b4 = (const float4*)(coef + 128);
  float4 av = a4[c4], bv = b4[c4];
  const float4* h4 = (const float4*)h2 + (size_t)g * NPG * 16;
  float4 s = {0.f, 0.f, 0.f, 0.f};
  float4 mx = {-1e30f, -1e30f, -1e30f, -1e30f};
  for (int n = rg; n < NPG; n += 16) {
    float4 v = h4[n * 16 + c4];
    float4 y;
    y.x = fmaxf(0.f, av.x * v.x + bv.x);
    y.y = fmaxf(0.f, av.y * v.y + bv.y);
    y.z = fmaxf(0.f, av.z * v.z + bv.z);
    y.w = fmaxf(0.f, av.w * v.w + bv.w);
    s.x += y.x; s.y += y.y; s.z += y.z; s.w += y.w;
    mx.x = fmaxf(mx.x, y.x); mx.y = fmaxf(mx.y, y.y);
    mx.z = fmaxf(mx.z, y.z); mx.w = fmaxf(mx.w, y.w);
  }
  psum4[rg * 16 + c4] = s;
  pmax4[rg * 16 + c4] = mx;
  __syncthreads();
  if (tid < 16) {
    float4 S = psum4[tid], M = pmax4[tid];
    for (int j = 1; j < 16; ++j) {
      float4 p = psum4[j * 16 + tid], q = pmax4[j * 16 + tid];
      S.x += p.x; S.y += p.y; S.z += p.z; S.w += p.w;
      M.x = fmaxf(M.x, q.x); M.y = fmaxf(M.y, q.y);
      M.z = fmaxf(M.z, q.z); M.w = fmaxf(M.w, q.w);
    }
    const float inv = 1.0f / NPG;
    ((float4*)emb)[tid] = make_float4(S.x * inv, S.y * inv, S.z * inv, S.w * inv);
    ((float4*)emb)[16 + tid] = M;
  }
  __syncthreads();
  if (tid < 32) {
    float acc = 0.0f;
#pragma unroll
    for (int k = 0; k < 128; ++k) acc += emb[k] * Wf1[k * 32 + tid];
    z[g * 32 + tid] = acc;
  }
}

// single block: BNf stats over z (G x 32) -> coeffs -> relu -> FC2 -> out
__global__ __launch_bounds__(256) void k_final(const float* __restrict__ z,
                                               const float* __restrict__ gf,
                                               const float* __restrict__ bef,
                                               const float* __restrict__ Wf2,
                                               const float* __restrict__ bf2,
                                               float* __restrict__ out, int G) {
  __shared__ float ss[32], qs[32], af[32], cf[32];
  __shared__ float w2s[64], b2s[2];
  int tid = threadIdx.x;
  if (tid < 32) { ss[tid] = 0.0f; qs[tid] = 0.0f; }
  if (tid < 64) w2s[tid] = Wf2[tid];
  if (tid < 2) b2s[tid] = bf2[tid];
  __syncthreads();
  const float4* z4 = (const float4*)z;
  int n4 = G * 8;
  float4 s = {0.f, 0.f, 0.f, 0.f}, q = {0.f, 0.f, 0.f, 0.f};
  for (int i = tid; i < n4; i += 256) {
    float4 v = z4[i];
    s.x += v.x; s.y += v.y; s.z += v.z; s.w += v.w;
    q.x += v.x * v.x; q.y += v.y * v.y; q.z += v.z * v.z; q.w += v.w * v.w;
  }
  int cg = (tid & 7) * 4;
  atomicAdd(&ss[cg + 0], s.x); atomicAdd(&ss[cg + 1], s.y);
  atomicAdd(&ss[cg + 2], s.z); atomicAdd(&ss[cg + 3], s.w);
  atomicAdd(&qs[cg + 0], q.x); atomicAdd(&qs[cg + 1], q.y);
  atomicAdd(&qs[cg + 2], q.z); atomicAdd(&qs[cg + 3], q.w);
  __syncthreads();
  if (tid < 32) {
    float invG = 1.0f / G;
    float m = ss[tid] * invG;
    float v = qs[tid] * invG - m * m;
    float a = gf[tid] * rsqrtf(v + EPS);
    af[tid] = a;
    cf[tid] = bef[tid] - m * a;
  }
  __syncthreads();
  for (int g = tid; g < G; g += 256) {
    float o0 = b2s[0], o1 = b2s[1];
    const float4* zr = z4 + g * 8;
#pragma unroll
    for (int kc = 0; kc < 8; ++kc) {
      float4 v = zr[kc];
      int j = 4 * kc;
      float y;
      y = fmaxf(0.f, af[j + 0] * v.x + cf[j + 0]);
      o0 += y * w2s[2 * (j + 0)]; o1 += y * w2s[2 * (j + 0) + 1];
      y = fmaxf(0.f, af[j + 1] * v.y + cf[j + 1]);
      o0 += y * w2s[2 * (j + 1)]; o1 += y * w2s[2 * (j + 1) + 1];
      y = fmaxf(0.f, af[j + 2] * v.z + cf[j + 2]);
      o0 += y * w2s[2 * (j + 2)]; o1 += y * w2s[2 * (j + 2) + 1];
      y = fmaxf(0.f, af[j + 3] * v.w + cf[j + 3]);
      o0 += y * w2s[2 * (j + 3)]; o1 += y * w2s[2 * (j + 3) + 1];
    }
    out[g * 2] = o0;
    out[g * 2 + 1] = o1;
  }
}

extern "C" void kernel_launch(void* const* d_in, const int* in_sizes, int n_in,
                              void* d_out, int out_size, void* d_ws, size_t ws_size,
                              hipStream_t stream) {
  const float* x   = (const float*)d_in[0];
  const int*   ei  = (const int*)d_in[1];
  const float* ew  = (const float*)d_in[2];
  // d_in[3]=batch (implicit), d_in[5]=b1, d_in[9]=b2, d_in[13]=bf1 cancel
  // under training-mode BN and are unused.
  const float* W1  = (const float*)d_in[4];
  const float* g1  = (const float*)d_in[6];
  const float* be1 = (const float*)d_in[7];
  const float* W2  = (const float*)d_in[8];
  const float* g2  = (const float*)d_in[10];
  const float* be2 = (const float*)d_in[11];
  const float* Wf1 = (const float*)d_in[12];
  const float* gf  = (const float*)d_in[14];
  const float* bef = (const float*)d_in[15];
  const float* Wf2 = (const float*)d_in[16];
  const float* bf2 = (const float*)d_in[17];

  int N = in_sizes[3];   // 118784
  int E = in_sizes[2];   // 3801088
  int G = N / NPG;       // 1024

  float* ws    = (float*)d_ws;
  float* stats = ws;         // 256
  float* coef  = ws + 256;   // 256
  float* h1    = ws + 512;
  float* h2    = h1 + (size_t)N * HID;
  float* z     = h2 + (size_t)N * HID2;
  float* out   = (float*)d_out;

  hipMemsetAsync(stats, 0, 256 * sizeof(float), stream);
  k_conv1<<<G, 256, 0, stream>>>(x, ei, ew, W1, h1, stats, N, E);
  k_coef<<<1, 64, 0, stream>>>(stats, stats + 32, g1, be1, coef, coef + 32,
                               1.0f / (float)N, HID);
  k_conv2<<<G, 256, 0, stream>>>(h1, ei, ew, W2, coef, h2, stats + 64, N, E);
  k_coef<<<1, 64, 0, stream>>>(stats + 64, stats + 128, g2, be2, coef + 64,
                               coef + 128, 1.0f / (float)N, HID2);
  k_pool<<<G, 256, 0, stream>>>(h2, coef, Wf1, z, N);
  k_final<<<1, 256, 0, stream>>>(z, gf, bef, Wf2, bf2, out, G);
}

// Round 4
// 270.295 us; speedup vs baseline: 1.6852x; 1.6852x over previous
//
#include <hip/hip_runtime.h>

#define NPG 116          // nodes per graph
#define DEGC 32          // edges per node
#define EPG (NPG * DEGC) // 3712 edges per graph
#define HID 32
#define HID2 64
#define EPS 1e-5f

#define APAD 120         // A row stride (floats), 16B-aligned rows
#define L1S 33           // l1 row stride
#define L2S 65           // l2 row stride
#define NJC 29           // 116 floats = 29 float4

#define FMA4(acc, a, b)                                                        \
  acc.x += (a).x * (b).x; acc.y += (a).y * (b).y;                              \
  acc.z += (a).z * (b).z; acc.w += (a).w * (b).w;

#define HSUM4(v) (((v).x + (v).y) + ((v).z + (v).w))

// ---------------------------------------------------------------------------
// ws layout (floats):
//   [0,256)    stats: s1[32] q1[32] s2[64] q2[64]   (memset to 0 each launch)
//   [256,512)  coefs: a1[32] c1[32] a2[64] c2[64]
//   [512, +32N)   h1  (conv1 output)
//   [..,  +64N)   h2  (conv2 output)
//   [..,  +32G)   z   (FC1 pre-BN)
// ---------------------------------------------------------------------------

// Fused: stage x tile -> lin1 = x@W1 -> build normalized A -> h1 = A@lin1
// -> h1 + BN1 stat partials.  One block (512 thr = 8 waves = 2/SIMD) per graph.
__global__ __launch_bounds__(512) void k_conv1(const float* __restrict__ x,
                                               const int* __restrict__ ei,
                                               const float* __restrict__ ew,
                                               const float* __restrict__ W1,
                                               float* __restrict__ h1,
                                               float* __restrict__ stats,
                                               int N, int E) {
  __shared__ __align__(16) float A[NPG * APAD];   // first used as x tile
  __shared__ float l1[NPG * L1S];
  __shared__ float degs[NPG];
  __shared__ float ss[HID], qs[HID];
  int g = blockIdx.x, tid = threadIdx.x;
  int nb = g * NPG, e0 = g * EPG;
  const int* rowp = ei;
  const int* colp = ei + E;

  for (int i = tid; i < NPG; i += 512) degs[i] = 1.0f;  // self-loop weight
  if (tid < HID) { ss[tid] = 0.0f; qs[tid] = 0.0f; }
  __syncthreads();

  // phase 1: stage x tile (float4), deg atomics, W1 column -> regs
  {
    const float4* xg = (const float4*)(x + (size_t)nb * 116);
    float4* xs4 = (float4*)A;
    for (int i = tid; i < 116 * NJC; i += 512) {
      int r = i / NJC, jc = i - r * NJC;
      xs4[r * 30 + jc] = xg[i];
    }
    for (int e = tid; e < EPG; e += 512) {
      int d = colp[e0 + e] - nb;
      atomicAdd(&degs[d], ew[e0 + e]);
    }
  }
  int c = tid & 31, rgrp = tid >> 5;  // 16 row groups, rows r = rgrp + 16*m
  float4 col[NJC];
#pragma unroll
  for (int kc = 0; kc < NJC; ++kc) {
    col[kc].x = W1[(4 * kc + 0) * 32 + c];
    col[kc].y = W1[(4 * kc + 1) * 32 + c];
    col[kc].z = W1[(4 * kc + 2) * 32 + c];
    col[kc].w = W1[(4 * kc + 3) * 32 + c];
  }
  __syncthreads();  // x tile staged, deg atomics done

  for (int i = tid; i < NPG; i += 512) degs[i] = rsqrtf(degs[i]);  // deg>=1

  // gemm1: l1[r][c] = sum_k x[r][k] * W1[k][c]
  const float4* A4 = (const float4*)A;
  for (int r = rgrp; r < NPG; r += 16) {
    const float4* pa = A4 + r * 30;
    float4 acc = {0.f, 0.f, 0.f, 0.f};
#pragma unroll
    for (int jc = 0; jc < NJC; ++jc) { FMA4(acc, pa[jc], col[jc]); }
    l1[r * L1S + c] = HSUM4(acc);
  }
  __syncthreads();  // all x-tile reads done -> reuse A

  {
    float4 z4 = {0.f, 0.f, 0.f, 0.f};
    float4* Az = (float4*)A;
    for (int i = tid; i < 116 * 30; i += 512) Az[i] = z4;
  }
  __syncthreads();

  // build A:  A[d][s] += dinv[s]*ew*dinv[d];  self loops A[i][i] += dinv[i]^2
  for (int e = tid; e < EPG; e += 512) {
    int eg = e0 + e;
    int s = rowp[eg] - nb, d = colp[eg] - nb;
    atomicAdd(&A[d * APAD + s], degs[s] * ew[eg] * degs[d]);
  }
  for (int i = tid; i < NPG; i += 512)
    atomicAdd(&A[i * APAD + i], degs[i] * degs[i]);
  // reload col regs with this lane's l1 column (l1 complete since last sync)
#pragma unroll
  for (int kc = 0; kc < NJC; ++kc) {
    col[kc].x = l1[(4 * kc + 0) * L1S + c];
    col[kc].y = l1[(4 * kc + 1) * L1S + c];
    col[kc].z = l1[(4 * kc + 2) * L1S + c];
    col[kc].w = l1[(4 * kc + 3) * L1S + c];
  }
  __syncthreads();  // A complete

  float s_ = 0.0f, q_ = 0.0f;
  for (int r = rgrp; r < NPG; r += 16) {
    const float4* pa = A4 + r * 30;
    float4 acc = {0.f, 0.f, 0.f, 0.f};
#pragma unroll
    for (int jc = 0; jc < NJC; ++jc) { FMA4(acc, pa[jc], col[jc]); }
    float v = HSUM4(acc);
    h1[(size_t)(nb + r) * HID + c] = v;
    s_ += v; q_ += v * v;
  }
  atomicAdd(&ss[c], s_);
  atomicAdd(&qs[c], q_);
  __syncthreads();
  if (tid < HID) {
    atomicAdd(&stats[tid], ss[tid]);
    atomicAdd(&stats[32 + tid], qs[tid]);
  }
}

// BN coefficients: a = g*rsqrt(var+eps), c = beta - mean*a
__global__ void k_coef(const float* __restrict__ s, const float* __restrict__ q,
                       const float* __restrict__ gamma, const float* __restrict__ beta,
                       float* __restrict__ a, float* __restrict__ cc,
                       float invN, int C) {
  int c = threadIdx.x;
  if (c < C) {
    float m = s[c] * invN;
    float v = q[c] * invN - m * m;
    float aa = gamma[c] * rsqrtf(v + EPS);
    a[c] = aa;
    cc[c] = beta[c] - m * aa;
  }
}

// Fused: ys = relu(a1*h1+c1) -> lin2 = ys@W2 -> build A -> h2 = A@lin2
// -> h2 + BN2 stat partials.  One block (512 thr) per graph.
__global__ __launch_bounds__(512) void k_conv2(const float* __restrict__ h1,
                                               const int* __restrict__ ei,
                                               const float* __restrict__ ew,
                                               const float* __restrict__ W2,
                                               const float* __restrict__ coef,
                                               float* __restrict__ h2,
                                               float* __restrict__ stats2,
                                               int N, int E) {
  __shared__ __align__(16) float A[NPG * APAD];
  __shared__ float4 ysv[NPG * 9];                 // ys, stride 36 floats
  __shared__ float l2[NPG * L2S];
  __shared__ float degs[NPG];
  __shared__ float ss[HID2], qs[HID2];
  int g = blockIdx.x, tid = threadIdx.x;
  int nb = g * NPG, e0 = g * EPG;
  const int* rowp = ei;
  const int* colp = ei + E;

  for (int i = tid; i < NPG; i += 512) degs[i] = 1.0f;
  if (tid < HID2) { ss[tid] = 0.0f; qs[tid] = 0.0f; }
  __syncthreads();

  // phase 1: stage ys = relu(a1*h1+c1), deg atomics, zero A
  {
    const float4* hg = (const float4*)(h1 + (size_t)nb * HID);
    const float4* a4p = (const float4*)coef;         // a1[32]
    const float4* c4p = (const float4*)(coef + 32);  // c1[32]
    for (int i = tid; i < 116 * 8; i += 512) {
      int r = i >> 3, kc = i & 7;
      float4 hv = hg[i];
      float4 av = a4p[kc], cv = c4p[kc];
      float4 y;
      y.x = fmaxf(0.f, av.x * hv.x + cv.x);
      y.y = fmaxf(0.f, av.y * hv.y + cv.y);
      y.z = fmaxf(0.f, av.z * hv.z + cv.z);
      y.w = fmaxf(0.f, av.w * hv.w + cv.w);
      ysv[r * 9 + kc] = y;
    }
    for (int e = tid; e < EPG; e += 512) {
      int d = colp[e0 + e] - nb;
      atomicAdd(&degs[d], ew[e0 + e]);
    }
    float4 z4 = {0.f, 0.f, 0.f, 0.f};
    float4* Az = (float4*)A;
    for (int i = tid; i < 116 * 30; i += 512) Az[i] = z4;
  }
  int c = tid & 63, rgrp = tid >> 6;  // 8 row groups, rows r = rgrp + 8*m
  float4 w2c[8];
#pragma unroll
  for (int kc = 0; kc < 8; ++kc) {
    w2c[kc].x = W2[(4 * kc + 0) * 64 + c];
    w2c[kc].y = W2[(4 * kc + 1) * 64 + c];
    w2c[kc].z = W2[(4 * kc + 2) * 64 + c];
    w2c[kc].w = W2[(4 * kc + 3) * 64 + c];
  }
  __syncthreads();

  for (int i = tid; i < NPG; i += 512) degs[i] = rsqrtf(degs[i]);
  __syncthreads();  // dinv ready, A zeroed

  // A-build atomics (latency) issued first, overlap gemm2 compute
  for (int e = tid; e < EPG; e += 512) {
    int eg = e0 + e;
    int s = rowp[eg] - nb, d = colp[eg] - nb;
    atomicAdd(&A[d * APAD + s], degs[s] * ew[eg] * degs[d]);
  }
  for (int i = tid; i < NPG; i += 512)
    atomicAdd(&A[i * APAD + i], degs[i] * degs[i]);

  // gemm2: l2[r][c] = sum_k ys[r][k]*W2[k][c]
  for (int r = rgrp; r < NPG; r += 8) {
    float4 acc = {0.f, 0.f, 0.f, 0.f};
#pragma unroll
    for (int kc = 0; kc < 8; ++kc) { FMA4(acc, ysv[r * 9 + kc], w2c[kc]); }
    l2[r * L2S + c] = HSUM4(acc);
  }
  __syncthreads();  // A + l2 complete

  float4 col[NJC];
#pragma unroll
  for (int kc = 0; kc < NJC; ++kc) {
    col[kc].x = l2[(4 * kc + 0) * L2S + c];
    col[kc].y = l2[(4 * kc + 1) * L2S + c];
    col[kc].z = l2[(4 * kc + 2) * L2S + c];
    col[kc].w = l2[(4 * kc + 3) * L2S + c];
  }
  const float4* A4 = (const float4*)A;
  float s_ = 0.0f, q_ = 0.0f;
  for (int r = rgrp; r < NPG; r += 8) {
    const float4* pa = A4 + r * 30;
    float4 acc = {0.f, 0.f, 0.f, 0.f};
#pragma unroll
    for (int jc = 0; jc < NJC; ++jc) { FMA4(acc, pa[jc], col[jc]); }
    float v = HSUM4(acc);
    h2[(size_t)(nb + r) * HID2 + c] = v;
    s_ += v; q_ += v * v;
  }
  atomicAdd(&ss[c], s_);
  atomicAdd(&qs[c], q_);
  __syncthreads();
  if (tid < HID2) {
    atomicAdd(&stats2[tid], ss[tid]);
    atomicAdd(&stats2[64 + tid], qs[tid]);
  }
}

// per-graph BN2+relu, mean/max pool, FC1 (emb[128] @ Wf1[128x32]) -> z
__global__ __launch_bounds__(256) void k_pool(const float* __restrict__ h2,
                                              const float* __restrict__ coef,
                                              const float* __restrict__ Wf1,
                                              float* __restrict__ z, int N) {
  __shared__ float4 psum4[256], pmax4[256];
  __shared__ __align__(16) float emb[128];
  int g = blockIdx.x, tid = threadIdx.x;
  int c4 = tid & 15, rg = tid >> 4;
  const float4* a4 = (const float4*)(coef + 64);
  const float4* b4 = (const float4*)(coef + 128);
  float4 av = a4[c4], bv = b4[c4];
  const float4* h4 = (const float4*)h2 + (size_t)g * NPG * 16;
  float4 s = {0.f, 0.f, 0.f, 0.f};
  float4 mx = {-1e30f, -1e30f, -1e30f, -1e30f};
  for (int n = rg; n < NPG; n += 16) {
    float4 v = h4[n * 16 + c4];
    float4 y;
    y.x = fmaxf(0.f, av.x * v.x + bv.x);
    y.y = fmaxf(0.f, av.y * v.y + bv.y);
    y.z = fmaxf(0.f, av.z * v.z + bv.z);
    y.w = fmaxf(0.f, av.w * v.w + bv.w);
    s.x += y.x; s.y += y.y; s.z += y.z; s.w += y.w;
    mx.x = fmaxf(mx.x, y.x); mx.y = fmaxf(mx.y, y.y);
    mx.z = fmaxf(mx.z, y.z); mx.w = fmaxf(mx.w, y.w);
  }
  psum4[rg * 16 + c4] = s;
  pmax4[rg * 16 + c4] = mx;
  __syncthreads();
  if (tid < 16) {
    float4 S = psum4[tid], M = pmax4[tid];
    for (int j = 1; j < 16; ++j) {
      float4 p = psum4[j * 16 + tid], q = pmax4[j * 16 + tid];
      S.x += p.x; S.y += p.y; S.z += p.z; S.w += p.w;
      M.x = fmaxf(M.x, q.x); M.y = fmaxf(M.y, q.y);
      M.z = fmaxf(M.z, q.z); M.w = fmaxf(M.w, q.w);
    }
    const float inv = 1.0f / NPG;
    ((float4*)emb)[tid] = make_float4(S.x * inv, S.y * inv, S.z * inv, S.w * inv);
    ((float4*)emb)[16 + tid] = M;
  }
  __syncthreads();
  if (tid < 32) {
    float acc = 0.0f;
#pragma unroll
    for (int k = 0; k < 128; ++k) acc += emb[k] * Wf1[k * 32 + tid];
    z[g * 32 + tid] = acc;
  }
}

// single block: BNf stats over z (G x 32) -> coeffs -> relu -> FC2 -> out
__global__ __launch_bounds__(256) void k_final(const float* __restrict__ z,
                                               const float* __restrict__ gf,
                                               const float* __restrict__ bef,
                                               const float* __restrict__ Wf2,
                                               const float* __restrict__ bf2,
                                               float* __restrict__ out, int G) {
  __shared__ float ss[32], qs[32], af[32], cf[32];
  __shared__ float w2s[64], b2s[2];
  int tid = threadIdx.x;
  if (tid < 32) { ss[tid] = 0.0f; qs[tid] = 0.0f; }
  if (tid < 64) w2s[tid] = Wf2[tid];
  if (tid < 2) b2s[tid] = bf2[tid];
  __syncthreads();
  const float4* z4 = (const float4*)z;
  int n4 = G * 8;
  float4 s = {0.f, 0.f, 0.f, 0.f}, q = {0.f, 0.f, 0.f, 0.f};
  for (int i = tid; i < n4; i += 256) {
    float4 v = z4[i];
    s.x += v.x; s.y += v.y; s.z += v.z; s.w += v.w;
    q.x += v.x * v.x; q.y += v.y * v.y; q.z += v.z * v.z; q.w += v.w * v.w;
  }
  int cg = (tid & 7) * 4;
  atomicAdd(&ss[cg + 0], s.x); atomicAdd(&ss[cg + 1], s.y);
  atomicAdd(&ss[cg + 2], s.z); atomicAdd(&ss[cg + 3], s.w);
  atomicAdd(&qs[cg + 0], q.x); atomicAdd(&qs[cg + 1], q.y);
  atomicAdd(&qs[cg + 2], q.z); atomicAdd(&qs[cg + 3], q.w);
  __syncthreads();
  if (tid < 32) {
    float invG = 1.0f / G;
    float m = ss[tid] * invG;
    float v = qs[tid] * invG - m * m;
    float a = gf[tid] * rsqrtf(v + EPS);
    af[tid] = a;
    cf[tid] = bef[tid] - m * a;
  }
  __syncthreads();
  for (int g = tid; g < G; g += 256) {
    float o0 = b2s[0], o1 = b2s[1];
    const float4* zr = z4 + g * 8;
#pragma unroll
    for (int kc = 0; kc < 8; ++kc) {
      float4 v = zr[kc];
      int j = 4 * kc;
      float y;
      y = fmaxf(0.f, af[j + 0] * v.x + cf[j + 0]);
      o0 += y * w2s[2 * (j + 0)]; o1 += y * w2s[2 * (j + 0) + 1];
      y = fmaxf(0.f, af[j + 1] * v.y + cf[j + 1]);
      o0 += y * w2s[2 * (j + 1)]; o1 += y * w2s[2 * (j + 1) + 1];
      y = fmaxf(0.f, af[j + 2] * v.z + cf[j + 2]);
      o0 += y * w2s[2 * (j + 2)]; o1 += y * w2s[2 * (j + 2) + 1];
      y = fmaxf(0.f, af[j + 3] * v.w + cf[j + 3]);
      o0 += y * w2s[2 * (j + 3)]; o1 += y * w2s[2 * (j + 3) + 1];
    }
    out[g * 2] = o0;
    out[g * 2 + 1] = o1;
  }
}

extern "C" void kernel_launch(void* const* d_in, const int* in_sizes, int n_in,
                              void* d_out, int out_size, void* d_ws, size_t ws_size,
                              hipStream_t stream) {
  const float* x   = (const float*)d_in[0];
  const int*   ei  = (const int*)d_in[1];
  const float* ew  = (const float*)d_in[2];
  // d_in[3]=batch (implicit), d_in[5]=b1, d_in[9]=b2, d_in[13]=bf1 cancel
  // under training-mode BN and are unused.
  const float* W1  = (const float*)d_in[4];
  const float* g1  = (const float*)d_in[6];
  const float* be1 = (const float*)d_in[7];
  const float* W2  = (const float*)d_in[8];
  const float* g2  = (const float*)d_in[10];
  const float* be2 = (const float*)d_in[11];
  const float* Wf1 = (const float*)d_in[12];
  const float* gf  = (const float*)d_in[14];
  const float* bef = (const float*)d_in[15];
  const float* Wf2 = (const float*)d_in[16];
  const float* bf2 = (const float*)d_in[17];

  int N = in_sizes[3];   // 118784
  int E = in_sizes[2];   // 3801088
  int G = N / NPG;       // 1024

  float* ws    = (float*)d_ws;
  float* stats = ws;         // 256
  float* coef  = ws + 256;   // 256
  float* h1    = ws + 512;
  float* h2    = h1 + (size_t)N * HID;
  float* z     = h2 + (size_t)N * HID2;
  float* out   = (float*)d_out;

  hipMemsetAsync(stats, 0, 256 * sizeof(float), stream);
  k_conv1<<<G, 512, 0, stream>>>(x, ei, ew, W1, h1, stats, N, E);
  k_coef<<<1, 64, 0, stream>>>(stats, stats + 32, g1, be1, coef, coef + 32,
                               1.0f / (float)N, HID);
  k_conv2<<<G, 512, 0, stream>>>(h1, ei, ew, W2, coef, h2, stats + 64, N, E);
  k_coef<<<1, 64, 0, stream>>>(stats + 64, stats + 128, g2, be2, coef + 64,
                               coef + 128, 1.0f / (float)N, HID2);
  k_pool<<<G, 256, 0, stream>>>(h2, coef, Wf1, z, N);
  k_final<<<1, 256, 0, stream>>>(z, gf, bef, Wf2, bf2, out, G);
}